// Round 7
// baseline (117.144 us; speedup 1.0000x reference)
//
#include <hip/hip_runtime.h>

// DIAGNOSTIC ROUND: R5's exact kernels, each repeated REPEAT× in-kernel to
// amplify execution time into rocprof's top-5 (launch overhead not amplified).
// Work is idempotent => output identical; dur_us this round is sacrificial.
#define REPEAT 20

#define N 2048
#define BS 16
#define QG 256             // queries per k1 block (4 per lane)
#define NQG (N / QG)       // 8 query groups
#define TS 128             // targets per k1 block
#define NTS (N / TS)       // 16 target slices
#define WAVES 4
#define TPB (WAVES * 64)   // 256 threads
#define TPW (TS / WAVES)   // 32 targets per wave
#define F4I (TPW / 4)      // 8 float4 iterations

__global__ __launch_bounds__(TPB) void addsloss_k1(
    const float* __restrict__ target,
    const float* __restrict__ mp,
    const int* __restrict__ idx,
    const float* __restrict__ H,
    float* __restrict__ wsmin)
{
    __shared__ float4 tlds[TS];          // (x, y, z, |t|^2)
    __shared__ float  pmin[WAVES][QG];

    const int bid  = blockIdx.x;
    const int b    = bid >> 7;        // / (NQG*NTS) = /128
    const int rem  = bid & 127;
    const int qg   = rem >> 4;        // / NTS
    const int ts   = rem & 15;        // % NTS
    const int tid  = threadIdx.x;
    const int wave = tid >> 6;
    const int lane = tid & 63;

    const int  cls = idx[b];
    const bool sym = (cls >= 0) && (cls <= 3);
    if (!sym) return;                 // non-sym handled entirely in k2

    const float* tb = target + (size_t)b * N * 3;
    const float* mb = mp     + (size_t)b * N * 3;
    const float* hb = H      + b * 16;

    for (int rep = 0; rep < REPEAT; ++rep) {
        // Stage 128 targets as (x,y,z,|t|^2).
        if (tid < TS) {
            const int t = ts * TS + tid;
            const float x = tb[t * 3 + 0];
            const float y = tb[t * 3 + 1];
            const float z = tb[t * 3 + 2];
            tlds[tid] = make_float4(x, y, z, x * x + y * y + z * z);
        }

        // 4 queries per lane; store -2*tf so the inner op is pure fma.
        float ngx[4], ngy[4], ngz[4];
        #pragma unroll
        for (int qi = 0; qi < 4; ++qi) {
            const int q = qg * QG + qi * 64 + lane;
            const float m0 = mb[q * 3 + 0];
            const float m1 = mb[q * 3 + 1];
            const float m2 = mb[q * 3 + 2];
            ngx[qi] = -2.0f * (hb[0] * m0 + hb[1]  * m1 + hb[2]  * m2 + hb[3]);
            ngy[qi] = -2.0f * (hb[4] * m0 + hb[5]  * m1 + hb[6]  * m2 + hb[7]);
            ngz[qi] = -2.0f * (hb[8] * m0 + hb[9]  * m1 + hb[10] * m2 + hb[11]);
        }

        __syncthreads();

        const float4* t4 = &tlds[wave * TPW];

        float acc[4][4];
        #pragma unroll
        for (int qi = 0; qi < 4; ++qi)
            #pragma unroll
            for (int ti = 0; ti < 4; ++ti) acc[qi][ti] = 3.4e38f;

        #pragma unroll
        for (int j = 0; j < F4I; ++j) {
            const float4 T0 = t4[j * 4 + 0];
            const float4 T1 = t4[j * 4 + 1];
            const float4 T2 = t4[j * 4 + 2];
            const float4 T3 = t4[j * 4 + 3];
            #pragma unroll
            for (int qi = 0; qi < 4; ++qi) {
                float h;
                h = T0.w; h = fmaf(ngx[qi], T0.x, h); h = fmaf(ngy[qi], T0.y, h);
                h = fmaf(ngz[qi], T0.z, h); acc[qi][0] = fminf(acc[qi][0], h);
                h = T1.w; h = fmaf(ngx[qi], T1.x, h); h = fmaf(ngy[qi], T1.y, h);
                h = fmaf(ngz[qi], T1.z, h); acc[qi][1] = fminf(acc[qi][1], h);
                h = T2.w; h = fmaf(ngx[qi], T2.x, h); h = fmaf(ngy[qi], T2.y, h);
                h = fmaf(ngz[qi], T2.z, h); acc[qi][2] = fminf(acc[qi][2], h);
                h = T3.w; h = fmaf(ngx[qi], T3.x, h); h = fmaf(ngy[qi], T3.y, h);
                h = fmaf(ngz[qi], T3.z, h); acc[qi][3] = fminf(acc[qi][3], h);
            }
        }

        #pragma unroll
        for (int qi = 0; qi < 4; ++qi)
            pmin[wave][qi * 64 + lane] =
                fminf(fminf(acc[qi][0], acc[qi][1]), fminf(acc[qi][2], acc[qi][3]));
        __syncthreads();

        float* wrow = wsmin + ((size_t)(b * NTS + ts)) * N + qg * QG;
        const float m = fminf(fminf(pmin[0][tid], pmin[1][tid]),
                              fminf(pmin[2][tid], pmin[3][tid]));
        wrow[tid] = m;

        __syncthreads();
        asm volatile("" ::: "memory");
    }
}

__global__ __launch_bounds__(512) void addsloss_k2(
    const float* __restrict__ target,
    const float* __restrict__ mp,
    const int* __restrict__ idx,
    const float* __restrict__ H,
    const float* __restrict__ wsmin,
    float* __restrict__ out)
{
    __shared__ float ps[8];
    const int b    = blockIdx.x;
    const int tid  = threadIdx.x;
    const int wave = tid >> 6;
    const int lane = tid & 63;

    const int  cls = idx[b];
    const bool sym = (cls >= 0) && (cls <= 3);

    const float* tb = target + (size_t)b * N * 3;
    const float* mb = mp     + (size_t)b * N * 3;
    const float* hb = H      + b * 16;

    for (int rep = 0; rep < REPEAT; ++rep) {
        const int q0 = tid * 4;   // queries [q0, q0+4)

        const float4* mq = reinterpret_cast<const float4*>(mb + (size_t)q0 * 3);
        const float4 A = mq[0], B = mq[1], C = mq[2];
        const float qx[4] = {A.x, A.w, B.z, C.y};
        const float qy[4] = {A.y, B.x, B.w, C.z};
        const float qz[4] = {A.z, B.y, C.x, C.w};

        float fx[4], fy[4], fz[4];
        #pragma unroll
        for (int i = 0; i < 4; ++i) {
            fx[i] = hb[0] * qx[i] + hb[1]  * qy[i] + hb[2]  * qz[i] + hb[3];
            fy[i] = hb[4] * qx[i] + hb[5]  * qy[i] + hb[6]  * qz[i] + hb[7];
            fz[i] = hb[8] * qx[i] + hb[9]  * qy[i] + hb[10] * qz[i] + hb[11];
        }

        float s = 0.0f;
        if (sym) {
            float4 m = make_float4(3.4e38f, 3.4e38f, 3.4e38f, 3.4e38f);
            #pragma unroll
            for (int t = 0; t < NTS; ++t) {
                const float4 v = *reinterpret_cast<const float4*>(
                    wsmin + ((size_t)(b * NTS + t)) * N + q0);
                m.x = fminf(m.x, v.x); m.y = fminf(m.y, v.y);
                m.z = fminf(m.z, v.z); m.w = fminf(m.w, v.w);
            }
            const float mm[4] = {m.x, m.y, m.z, m.w};
            #pragma unroll
            for (int i = 0; i < 4; ++i) {
                const float c = fx[i] * fx[i] + fy[i] * fy[i] + fz[i] * fz[i];
                s += sqrtf(fmaxf(0.0f, c + mm[i]));
            }
        } else {
            const float4* tq = reinterpret_cast<const float4*>(tb + (size_t)q0 * 3);
            const float4 D = tq[0], E = tq[1], F = tq[2];
            const float tx[4] = {D.x, D.w, E.z, F.y};
            const float ty[4] = {D.y, E.x, E.w, F.z};
            const float tz[4] = {D.z, E.y, F.x, F.w};
            #pragma unroll
            for (int i = 0; i < 4; ++i) {
                const float dx = fx[i] - tx[i];
                const float dy = fy[i] - ty[i];
                const float dz = fz[i] - tz[i];
                s += sqrtf(dx * dx + dy * dy + dz * dz);
            }
        }

        #pragma unroll
        for (int off = 32; off > 0; off >>= 1) s += __shfl_down(s, off);
        if (lane == 0) ps[wave] = s;
        __syncthreads();
        if (tid == 0) {
            float tot = 0.0f;
            #pragma unroll
            for (int w = 0; w < 8; ++w) tot += ps[w];
            out[b] = tot * (1.0f / (float)N);
        }
        __syncthreads();
        asm volatile("" ::: "memory");
    }
}

extern "C" void kernel_launch(void* const* d_in, const int* in_sizes, int n_in,
                              void* d_out, int out_size, void* d_ws, size_t ws_size,
                              hipStream_t stream) {
    const float* target = (const float*)d_in[0];   // [16, 2048, 3]
    const float* mp     = (const float*)d_in[1];   // [16, 2048, 3]
    const int*   idx    = (const int*)  d_in[2];   // [16, 1]
    const float* H      = (const float*)d_in[3];   // [16, 4, 4]
    float*       out    = (float*)d_out;           // [16]
    float*       wsmin  = (float*)d_ws;            // BS*NTS*N floats = 2 MB

    addsloss_k1<<<BS * NQG * NTS, TPB, 0, stream>>>(target, mp, idx, H, wsmin);
    addsloss_k2<<<BS, 512, 0, stream>>>(target, mp, idx, H, wsmin, out);
}

// Round 8
// 21.973 us; speedup vs baseline: 5.3312x; 5.3312x over previous
//
#include <hip/hip_runtime.h>

#define N 2048
#define BS 16
#define NQG 16             // query groups per batch
#define QG 128             // queries per group (2 per lane)
#define WAVES 8
#define TPB (WAVES * 64)   // 512 threads
#define TPW (N / WAVES)    // 256 targets per wave
#define QPL 2

// Single compute dispatch. Each block = (batch, 128-query group): scans ALL
// targets (staged in LDS), produces one partial sum. Last block per batch
// (device-scope atomic counter) combines the 16 partials in fixed order.
// ws: partial[256] floats at offset 0; cnt[16] uints at byte offset 1024
// (zeroed by hipMemsetAsync each call).
__global__ __launch_bounds__(TPB) void addsloss_fused(
    const float* __restrict__ target,
    const float* __restrict__ mp,
    const int* __restrict__ idx,
    const float* __restrict__ H,
    float* __restrict__ partial,
    unsigned int* __restrict__ cnt,
    float* __restrict__ out)
{
    __shared__ float4 tlds[N];           // (x,y,z,|t|^2)  32 KB
    __shared__ float  pmin[WAVES][QG];   // 4 KB
    __shared__ float  dsum[QG];          // 512 B

    const int bid  = blockIdx.x;
    const int b    = bid >> 4;         // / NQG
    const int qg   = bid & 15;         // % NQG
    const int tid  = threadIdx.x;
    const int wave = tid >> 6;
    const int lane = tid & 63;

    const int  cls = idx[b];
    const bool sym = (cls >= 0) && (cls <= 3);

    const float* tb = target + (size_t)b * N * 3;
    const float* mb = mp     + (size_t)b * N * 3;
    const float* hb = H      + b * 16;

    if (sym) {
        // Stage all 2048 targets as (x,y,z,|t|^2).
        for (int i = tid; i < N; i += TPB) {
            const float x = tb[i * 3 + 0];
            const float y = tb[i * 3 + 1];
            const float z = tb[i * 3 + 2];
            tlds[i] = make_float4(x, y, z, x * x + y * y + z * z);
        }

        // 2 queries per lane (q_local = lane and lane+64); store -2*tf.
        float ngx[QPL], ngy[QPL], ngz[QPL];
        #pragma unroll
        for (int qi = 0; qi < QPL; ++qi) {
            const int q = qg * QG + qi * 64 + lane;
            const float m0 = mb[q * 3 + 0];
            const float m1 = mb[q * 3 + 1];
            const float m2 = mb[q * 3 + 2];
            ngx[qi] = -2.0f * (hb[0] * m0 + hb[1]  * m1 + hb[2]  * m2 + hb[3]);
            ngy[qi] = -2.0f * (hb[4] * m0 + hb[5]  * m1 + hb[6]  * m2 + hb[7]);
            ngz[qi] = -2.0f * (hb[8] * m0 + hb[9]  * m1 + hb[10] * m2 + hb[11]);
        }

        __syncthreads();

        // This wave scans targets [wave*256, wave*256+256).
        const float4* t4 = &tlds[wave * TPW];

        float acc[QPL][4];
        #pragma unroll
        for (int qi = 0; qi < QPL; ++qi)
            #pragma unroll
            for (int ti = 0; ti < 4; ++ti) acc[qi][ti] = 3.4e38f;

        #pragma unroll 2
        for (int j = 0; j < TPW / 4; ++j) {
            const float4 T0 = t4[j * 4 + 0];
            const float4 T1 = t4[j * 4 + 1];
            const float4 T2 = t4[j * 4 + 2];
            const float4 T3 = t4[j * 4 + 3];
            #pragma unroll
            for (int qi = 0; qi < QPL; ++qi) {
                float h;
                h = T0.w; h = fmaf(ngx[qi], T0.x, h); h = fmaf(ngy[qi], T0.y, h);
                h = fmaf(ngz[qi], T0.z, h); acc[qi][0] = fminf(acc[qi][0], h);
                h = T1.w; h = fmaf(ngx[qi], T1.x, h); h = fmaf(ngy[qi], T1.y, h);
                h = fmaf(ngz[qi], T1.z, h); acc[qi][1] = fminf(acc[qi][1], h);
                h = T2.w; h = fmaf(ngx[qi], T2.x, h); h = fmaf(ngy[qi], T2.y, h);
                h = fmaf(ngz[qi], T2.z, h); acc[qi][2] = fminf(acc[qi][2], h);
                h = T3.w; h = fmaf(ngx[qi], T3.x, h); h = fmaf(ngy[qi], T3.y, h);
                h = fmaf(ngz[qi], T3.z, h); acc[qi][3] = fminf(acc[qi][3], h);
            }
        }

        #pragma unroll
        for (int qi = 0; qi < QPL; ++qi)
            pmin[wave][qi * 64 + lane] =
                fminf(fminf(acc[qi][0], acc[qi][1]), fminf(acc[qi][2], acc[qi][3]));
        __syncthreads();

        // Threads 0..127: finalize their own query (tid<64 -> its q0,
        // 64<=tid<128 -> its q1; both hold the matching ng registers).
        if (tid < QG) {
            float m = pmin[0][tid];
            #pragma unroll
            for (int w = 1; w < WAVES; ++w) m = fminf(m, pmin[w][tid]);
            const int qi = tid >> 6;
            const float c = 0.25f * (ngx[qi] * ngx[qi] + ngy[qi] * ngy[qi]
                                     + ngz[qi] * ngz[qi]);   // |tf|^2
            dsum[tid] = sqrtf(fmaxf(0.0f, c + m));
        }
    } else {
        // Non-symmetric: direct distance to same-index target.
        if (tid < QG) {
            const int q = qg * QG + tid;
            const float m0 = mb[q * 3 + 0];
            const float m1 = mb[q * 3 + 1];
            const float m2 = mb[q * 3 + 2];
            const float fx = hb[0] * m0 + hb[1]  * m1 + hb[2]  * m2 + hb[3];
            const float fy = hb[4] * m0 + hb[5]  * m1 + hb[6]  * m2 + hb[7];
            const float fz = hb[8] * m0 + hb[9]  * m1 + hb[10] * m2 + hb[11];
            const float dx = fx - tb[q * 3 + 0];
            const float dy = fy - tb[q * 3 + 1];
            const float dz = fz - tb[q * 3 + 2];
            dsum[tid] = sqrtf(dx * dx + dy * dy + dz * dz);
        }
    }

    __syncthreads();

    // Deterministic block sum of dsum[0..127] by wave 0; then the last
    // finishing block of this batch reduces the 16 partials in fixed order.
    if (wave == 0) {
        float s = dsum[lane] + dsum[lane + 64];
        #pragma unroll
        for (int off = 32; off > 0; off >>= 1) s += __shfl_down(s, off);
        if (lane == 0) {
            partial[bid] = s;
            __threadfence();
            const unsigned int old = atomicAdd(&cnt[b], 1u);
            if (old == NQG - 1) {
                __threadfence();
                float tot = 0.0f;
                #pragma unroll
                for (int p = 0; p < NQG; ++p) tot += partial[b * NQG + p];
                out[b] = tot * (1.0f / (float)N);
            }
        }
    }
}

extern "C" void kernel_launch(void* const* d_in, const int* in_sizes, int n_in,
                              void* d_out, int out_size, void* d_ws, size_t ws_size,
                              hipStream_t stream) {
    const float* target = (const float*)d_in[0];   // [16, 2048, 3]
    const float* mp     = (const float*)d_in[1];   // [16, 2048, 3]
    const int*   idx    = (const int*)  d_in[2];   // [16, 1]
    const float* H      = (const float*)d_in[3];   // [16, 4, 4]
    float*       out    = (float*)d_out;           // [16]
    float*        partial = (float*)d_ws;                          // 256 floats
    unsigned int* cntp    = (unsigned int*)((char*)d_ws + 1024);   // 16 uints

    hipMemsetAsync((char*)d_ws + 1024, 0, 64, stream);   // zero batch counters
    addsloss_fused<<<BS * NQG, TPB, 0, stream>>>(target, mp, idx, H,
                                                 partial, cntp, out);
}